// Round 9
// baseline (225.344 us; speedup 1.0000x reference)
//
#include <hip/hip_runtime.h>
#include <hip/hip_bf16.h>

// out[b,n] = prod_d psi((x[b,d]-c[n,d])/s[n,d]),  psi(z)=(1-z^2)exp(-z^2/2)
// Factorization: prod psi = [prod(1-z^2)] * exp(-0.5*sum z^2) per 16-d group
// (per-lane-half partial product <= 80^8 ~ 1.7e15, merged ~3e30 < fp32 max).
// fp32-only: f16/bf16 in the exponent -> rel err ~1e-3 * sum(z^2)~128 ->
// output scale factor e^0.064, far above the absmax threshold. No MFMA path.
//
// R9 = R8 (lane=n, wave=8-row b-strip, params VGPR-resident per 16-d chunk,
// 8 waves/SIMD) + explicit two-deep x prefetch: R8 exposed ~32 s_load
// latency windows per wave (x slice loaded and consumed immediately per
// (h,bi); 128 SGPRs needed to hoist all -> compiler can't). Double-buffer
// holds exactly one slice ahead (32 SGPRs), hiding lgkm latency under the
// previous slice's 32 pk-ops.
//
// Launch-bounds rule (measured R2/R4/R5): 2nd arg w caps VGPR at 256/w.
// w=4 -> cap 64; budget: params 32 + acc 8 + p/s2 4 + temps ~12 = ~56
// (x lives in SGPRs via wave-uniform addresses).

#define DD 64
#define BSTRIP 8    // b rows per wave

typedef float v2f __attribute__((ext_vector_type(2)));

__global__ __launch_bounds__(256)
void prep(const float* __restrict__ c, const float* __restrict__ s,
          float4* __restrict__ pp, int N) {
    int i = blockIdx.x * 256 + threadIdx.x;   // over (DD/2)*N
    if (i < (DD / 2) * N) {
        int dp = i / N, n = i - dp * N;
        float r0 = 1.0f / s[n * DD + 2 * dp];
        float r1 = 1.0f / s[n * DD + 2 * dp + 1];
        pp[i] = make_float4(c[n * DD + 2 * dp] * r0,
                            c[n * DD + 2 * dp + 1] * r1, r0, r1);
    }
}

__global__ __launch_bounds__(256, 4)
void wavelet_kernel(const float* __restrict__ x,
                    const float4* __restrict__ pp,
                    float* __restrict__ out, int B, int N) {
    int t = threadIdx.x;
    int lane = t & 63;
    int wv = __builtin_amdgcn_readfirstlane(t >> 6);   // wave-uniform
    int n = blockIdx.y * 64 + lane;                    // lane-private column
    int b0 = (blockIdx.x * 4 + wv) * BSTRIP;           // wave-uniform strip

    const float4* pcol = pp + n;                 // pp[dp*N + n], lane-coalesced
    const float4* xs4 = (const float4*)(x + (size_t)b0 * DD);  // uniform base

    float acc[BSTRIP];
#pragma unroll
    for (int bi = 0; bi < BSTRIP; ++bi) acc[bi] = 1.0f;

    // x slice double buffer (wave-uniform addresses -> SGPR s_loads).
    // slice (bi,h) = 16 floats = 4 float4 at xs4[bi*4 + h .. ] -- row bi
    // has 16 float4s; chunk h covers quads h*4..h*4+3? No: chunk h is
    // elements h*16..h*16+15 = float4 indices bi*16 + h*4 + {0..3}.
    float4 Xc0, Xc1, Xc2, Xc3, Xn0, Xn1, Xn2, Xn3;
    Xc0 = xs4[0]; Xc1 = xs4[1]; Xc2 = xs4[2]; Xc3 = xs4[3];

#pragma unroll
    for (int h = 0; h < 4; ++h) {          // 4 chunks of 16 d (overflow group)
        // params for this chunk: VGPR-resident, reused by all 8 b rows
        v2f cp[8], rs[8];
#pragma unroll
        for (int i = 0; i < 8; ++i) {
            float4 q = pcol[(size_t)(h * 8 + i) * N];  // coalesced dwordx4
            cp[i] = (v2f){q.x, q.y};
            rs[i] = (v2f){q.z, q.w};
        }

#pragma unroll
        for (int bi = 0; bi < BSTRIP; ++bi) {
            // issue next slice's loads before consuming current slice
            if (bi < BSTRIP - 1) {
                const float4* q = xs4 + (bi + 1) * 16 + h * 4;
                Xn0 = q[0]; Xn1 = q[1]; Xn2 = q[2]; Xn3 = q[3];
            } else if (h < 3) {
                const float4* q = xs4 + (h + 1) * 4;   // (bi=0, h+1)
                Xn0 = q[0]; Xn1 = q[1]; Xn2 = q[2]; Xn3 = q[3];
            }

            float xs[16] = {Xc0.x, Xc0.y, Xc0.z, Xc0.w,
                            Xc1.x, Xc1.y, Xc1.z, Xc1.w,
                            Xc2.x, Xc2.y, Xc2.z, Xc2.w,
                            Xc3.x, Xc3.y, Xc3.z, Xc3.w};
            v2f p  = {1.0f, 1.0f};
            v2f s2 = {0.0f, 0.0f};
#pragma unroll
            for (int k = 0; k < 8; ++k) {          // 8 d-pairs = 16 d
                v2f xv = {xs[2 * k], xs[2 * k + 1]};
                v2f z = __builtin_elementwise_fma(xv, rs[k], -cp[k]);
                v2f w = z * z;
                p = __builtin_elementwise_fma(-w, p, p);
                s2 += w;
            }
            // exp(-0.5*s) = exp2(-0.72134752*s), one per 16-d group
            acc[bi] *= (p.x * p.y) *
                       __builtin_exp2f(-0.72134752f * (s2.x + s2.y));

            Xc0 = Xn0; Xc1 = Xn1; Xc2 = Xn2; Xc3 = Xn3;  // rotate buffer
        }
    }

    // stores: lanes = consecutive n -> coalesced
#pragma unroll
    for (int bi = 0; bi < BSTRIP; ++bi)
        out[(size_t)(b0 + bi) * N + n] = acc[bi];
}

extern "C" void kernel_launch(void* const* d_in, const int* in_sizes, int n_in,
                              void* d_out, int out_size, void* d_ws, size_t ws_size,
                              hipStream_t stream) {
    const float* x = (const float*)d_in[0];
    const float* c = (const float*)d_in[1];
    const float* s = (const float*)d_in[2];
    float* out = (float*)d_out;

    int B = in_sizes[0] / DD;    // 8192
    int N = in_sizes[1] / DD;    // 512

    float4* pp = (float4*)d_ws;  // (DD/2)*N*16 B = 256 KB

    int total = (DD / 2) * N;
    prep<<<(total + 255) / 256, 256, 0, stream>>>(c, s, pp, N);

    // grid: x = b-strip groups (4 waves x 8 rows = 32 rows/block), y = n/64
    dim3 grid(B / (4 * BSTRIP), N / 64);   // 256 x 8 = 2048 blocks
    wavelet_kernel<<<grid, 256, 0, stream>>>(x, pp, out, B, N);
}

// Round 10
// 86.358 us; speedup vs baseline: 2.6094x; 2.6094x over previous
//
#include <hip/hip_runtime.h>
#include <hip/hip_bf16.h>

// out[b,n] = prod_d psi((x[b,d]-c[n,d])/s[n,d]),  psi(z)=(1-z^2)exp(-z^2/2)
// Factorization: prod psi = [prod(1-z^2)] * exp(-0.5*sum z^2) per 16-d group
// (per-lane-half partial product <= 80^8 ~ 1.7e15, merged ~3e30 < fp32 max).
// fp32-only: f16/bf16 anywhere in the exponent path scales outputs by
// ~e^0.064 — 11 orders above the 1.7e-18 absmax threshold. No MFMA path.
//
// R10 = R8 (lane=n, wave=8-row b-strip, params VGPR-resident per 16-d
// chunk, 8 waves/SIMD) with x moved to LDS:
//  - block stages its 32-row x strip (8 KB) once, coalesced.
//  - hot loop reads x via ds_read_b128 at wave-uniform addresses
//    (same-address broadcast = conflict-free); compiler pipelines ds_read
//    with fine-grained lgkmcnt (m97 pattern) — replaces R8's 32 exposed
//    global-load windows per wave.
//  - R9 lesson: NO explicit register rotation (pushed past the 64-VGPR
//    cap -> scratch demotion, FETCH 400 MB, 225 us). Compiler owns the
//    schedule.
// VALU floor: 1.07B scalar ops / 128 per pk-inst / 1024 SIMD * 4 cyc
// = 13.7 us (+ ~10% exp folds).
//
// Launch-bounds rule (measured R2/R4/R5): 2nd arg w caps VGPR at 256/w.
// w=4 -> cap 64; budget: params 32 + acc 8 + temps ~16 = ~56.

#define DD 64
#define BSTRIP 8    // b rows per wave
#define BROWS 32    // b rows per block (4 waves)

typedef float v2f __attribute__((ext_vector_type(2)));

__global__ __launch_bounds__(256)
void prep(const float* __restrict__ c, const float* __restrict__ s,
          float4* __restrict__ pp, int N) {
    int i = blockIdx.x * 256 + threadIdx.x;   // over (DD/2)*N
    if (i < (DD / 2) * N) {
        int dp = i / N, n = i - dp * N;
        float r0 = 1.0f / s[n * DD + 2 * dp];
        float r1 = 1.0f / s[n * DD + 2 * dp + 1];
        pp[i] = make_float4(c[n * DD + 2 * dp] * r0,
                            c[n * DD + 2 * dp + 1] * r1, r0, r1);
    }
}

__global__ __launch_bounds__(256, 4)
void wavelet_kernel(const float* __restrict__ x,
                    const float4* __restrict__ pp,
                    float* __restrict__ out, int B, int N) {
    __shared__ float lx[BROWS * DD];          // 8 KB x strip

    int t = threadIdx.x;
    int lane = t & 63;
    int wv = __builtin_amdgcn_readfirstlane(t >> 6);   // wave-uniform
    int n = blockIdx.y * 64 + lane;                    // lane-private column
    int b0 = blockIdx.x * BROWS;                       // block's b strip

    // stage x strip: thread t loads 8 consecutive floats (two float4),
    // per-wave addresses contiguous -> coalesced dwordx4.
    {
        int row = t >> 3, col = (t & 7) * 8;
        const float4* src = (const float4*)(x + (size_t)(b0 + row) * DD + col);
        float4* dst = (float4*)(lx + row * DD + col);
        dst[0] = src[0];
        dst[1] = src[1];
    }
    __syncthreads();

    const float4* pcol = pp + n;              // pp[dp*N + n], lane-coalesced
    const float4* lxs = (const float4*)(lx + (wv * BSTRIP) * DD);

    float acc[BSTRIP];
#pragma unroll
    for (int bi = 0; bi < BSTRIP; ++bi) acc[bi] = 1.0f;

#pragma unroll
    for (int h = 0; h < 4; ++h) {          // 4 chunks of 16 d (overflow group)
        // params for this chunk: VGPR-resident, reused by all 8 b rows
        v2f cp[8], rs[8];
#pragma unroll
        for (int i = 0; i < 8; ++i) {
            float4 q = pcol[(size_t)(h * 8 + i) * N];  // coalesced dwordx4
            cp[i] = (v2f){q.x, q.y};
            rs[i] = (v2f){q.z, q.w};
        }

#pragma unroll
        for (int bi = 0; bi < BSTRIP; ++bi) {
            // x slice from LDS: wave-uniform address -> broadcast, no
            // bank conflicts; ds_read_b128 x4, compiler-pipelined lgkmcnt.
            const float4* xq = lxs + bi * (DD / 4) + h * 4;
            float4 X0 = xq[0];
            float4 X1 = xq[1];
            float4 X2 = xq[2];
            float4 X3 = xq[3];
            float xs[16] = {X0.x, X0.y, X0.z, X0.w,
                            X1.x, X1.y, X1.z, X1.w,
                            X2.x, X2.y, X2.z, X2.w,
                            X3.x, X3.y, X3.z, X3.w};
            v2f p  = {1.0f, 1.0f};
            v2f s2 = {0.0f, 0.0f};
#pragma unroll
            for (int k = 0; k < 8; ++k) {          // 8 d-pairs = 16 d
                v2f xv = {xs[2 * k], xs[2 * k + 1]};
                v2f z = __builtin_elementwise_fma(xv, rs[k], -cp[k]);
                v2f w = z * z;
                p = __builtin_elementwise_fma(-w, p, p);
                s2 += w;
            }
            // exp(-0.5*s) = exp2(-0.72134752*s), one per 16-d group
            acc[bi] *= (p.x * p.y) *
                       __builtin_exp2f(-0.72134752f * (s2.x + s2.y));
        }
    }

    // stores: lanes = consecutive n -> coalesced
    int bb = b0 + wv * BSTRIP;
#pragma unroll
    for (int bi = 0; bi < BSTRIP; ++bi)
        out[(size_t)(bb + bi) * N + n] = acc[bi];
}

extern "C" void kernel_launch(void* const* d_in, const int* in_sizes, int n_in,
                              void* d_out, int out_size, void* d_ws, size_t ws_size,
                              hipStream_t stream) {
    const float* x = (const float*)d_in[0];
    const float* c = (const float*)d_in[1];
    const float* s = (const float*)d_in[2];
    float* out = (float*)d_out;

    int B = in_sizes[0] / DD;    // 8192
    int N = in_sizes[1] / DD;    // 512

    float4* pp = (float4*)d_ws;  // (DD/2)*N*16 B = 256 KB

    int total = (DD / 2) * N;
    prep<<<(total + 255) / 256, 256, 0, stream>>>(c, s, pp, N);

    // grid: x = b strips of 32 rows, y = n tiles of 64
    dim3 grid(B / BROWS, N / 64);   // 256 x 8 = 2048 blocks
    wavelet_kernel<<<grid, 256, 0, stream>>>(x, pp, out, B, N);
}